// Round 12
// baseline (2704.787 us; speedup 1.0000x reference)
//
#include <hip/hip_runtime.h>

typedef __attribute__((ext_vector_type(8))) short bf16x8;
typedef __attribute__((ext_vector_type(4))) float f32x4;
typedef __attribute__((ext_vector_type(16))) float f32x16;

// B=64, T=512, D=256, H=512, L=4, 4H=2048
// 32 wgs/layer (16 hcols), 256 thr = 4 waves. Grid 128. 32x32x16 MFMA (v11
// layouts, verified). v12: cross-step W-prefetch into registers + counted
// early-flag + poll/gate overlap. Dependency graph identical to v9/v11.
#define WPL 32
#define NT 256
#define RING 8

__device__ __forceinline__ unsigned short f2bf(float f) {
  unsigned int u = __float_as_uint(f);
  u += 0x7FFFu + ((u >> 16) & 1u);
  return (unsigned short)(u >> 16);
}
__device__ __forceinline__ float sigmoid_fast(float x) {
  return __builtin_amdgcn_rcpf(1.0f + __builtin_amdgcn_exp2f(-1.4426950408889634f * x));
}
__device__ __forceinline__ float tanh_fast(float x) {
  return 1.0f - 2.0f * __builtin_amdgcn_rcpf(
                           1.0f + __builtin_amdgcn_exp2f(2.885390081777927f * x));
}
__device__ __forceinline__ void wait_vm0() {
  asm volatile("s_waitcnt vmcnt(0)" ::: "memory");
  __builtin_amdgcn_sched_barrier(0);
}
#define WAITVM(N)                                         \
  do {                                                    \
    asm volatile("s_waitcnt vmcnt(" #N ")" ::: "memory"); \
    __builtin_amdgcn_sched_barrier(0);                    \
  } while (0)

template <int MODE>  // 0 = cached (x), 2 = sc0 sc1 (LLC h)
__device__ __forceinline__ void ldA(bf16x8& d, int voff, const unsigned short* base) {
  if constexpr (MODE == 0)
    asm volatile("global_load_dwordx4 %0, %1, %2"
                 : "=v"(d) : "v"(voff), "s"(base));
  else
    asm volatile("global_load_dwordx4 %0, %1, %2 sc0 sc1"
                 : "=v"(d) : "v"(voff), "s"(base));
}
__device__ __forceinline__ unsigned ld_flag(const unsigned* p) {
  unsigned v;
  asm volatile("global_load_dword %0, %1, off sc0 sc1\n\ts_waitcnt vmcnt(0)"
               : "=v"(v) : "v"(p) : "memory");
  return v;
}
__device__ __forceinline__ void st16_coh(void* p, f32x4 v) {
  asm volatile("global_store_dwordx4 %0, %1, off sc0 sc1" :: "v"(p), "v"(v) : "memory");
}
__device__ __forceinline__ void st4_coh(void* p, unsigned v) {
  asm volatile("global_store_dword %0, %1, off sc0 sc1" :: "v"(p), "v"(v) : "memory");
}

// ---------------- prep kernels (v11, verified) ----------------

__global__ void cvt_x_kernel(const float* __restrict__ x,
                             unsigned short* __restrict__ xf) {
  int tid = blockIdx.x * 256 + threadIdx.x;  // 1,048,576
  int t     = tid >> 11;
  int inner = tid & 2047;
  int lane  = inner & 63;
  int vm    = (inner >> 6) & 1;
  int ks    = inner >> 7;
  int b = vm * 32 + (lane & 31);
  int d = ks * 16 + (lane >> 5) * 8;
  const float* s = x + ((size_t)b * 512 + t) * 256 + d;
  f32x4 v0 = *(const f32x4*)s;
  f32x4 v1 = *(const f32x4*)(s + 4);
  bf16x8 o;
  o[0] = (short)f2bf(v0[0]); o[1] = (short)f2bf(v0[1]);
  o[2] = (short)f2bf(v0[2]); o[3] = (short)f2bf(v0[3]);
  o[4] = (short)f2bf(v1[0]); o[5] = (short)f2bf(v1[1]);
  o[6] = (short)f2bf(v1[2]); o[7] = (short)f2bf(v1[3]);
  *(bf16x8*)(xf + (size_t)t * 16384 + (size_t)inner * 8) = o;
}

__global__ void cvt_w_kernel(const float* __restrict__ W,
                             const float* __restrict__ U,
                             unsigned short* __restrict__ dst,
                             int C2, int split) {
  int tid = blockIdx.x * 256 + threadIdx.x;
  int lane = tid & 63;
  int c    = (tid >> 6) % C2;
  int rest = tid / (64 * C2);
  int vn = rest & 1;
  int w  = rest >> 1;
  int zz = vn * 32 + (lane & 31);
  int row = (zz >> 4) * 512 + w * 16 + (zz & 15);
  int k   = c * 16 + (lane >> 5) * 8;
  const float* s = (k < split) ? (W + (size_t)row * split + k)
                               : (U + (size_t)row * 512 + (k - split));
  f32x4 v0 = *(const f32x4*)s;
  f32x4 v1 = *(const f32x4*)(s + 4);
  bf16x8 o;
  o[0] = (short)f2bf(v0[0]); o[1] = (short)f2bf(v0[1]);
  o[2] = (short)f2bf(v0[2]); o[3] = (short)f2bf(v0[3]);
  o[4] = (short)f2bf(v1[0]); o[5] = (short)f2bf(v1[1]);
  o[6] = (short)f2bf(v1[2]); o[7] = (short)f2bf(v1[3]);
  *(bf16x8*)(dst + (size_t)tid * 8) = o;
}

__global__ void bias_kernel(const float* __restrict__ bw,
                            const float* __restrict__ bu,
                            float* __restrict__ dst) {
  int i = blockIdx.x * 256 + threadIdx.x;  // 2048
  dst[i] = bw[i] + bu[i];
}

__global__ void zero_flags(unsigned int* __restrict__ p) {
  int i = blockIdx.x * 256 + threadIdx.x;  // 2048
  p[i] = 0u;
}

// ---------------- GEMM pieces ----------------

// pure-register W-GEMM over NPF prefetched chunks (B from LDS)
template <int NPF>
__device__ __forceinline__ void wgemm(const bf16x8* aw, const char* bg, f32x16& acc) {
#pragma unroll
  for (int c = 0; c < NPF; ++c) {
    bf16x8 bb = *(const bf16x8*)(bg + c * 1024);
    acc = __builtin_amdgcn_mfma_f32_32x32x16_bf16(aw[c], bb, acc, 0, 0, 0);
  }
}

// stream: C2 chunks over (a1: first C1) then a2; requires vmcnt==0 at the
// issue; ladder exact. bg pre-offset to the stream's first chunk.
template <int C1, int C2, int M1, int M2>
__device__ __forceinline__ void stream_issue3(bf16x8 av[3][4],
                                              const unsigned short* a1,
                                              const unsigned short* a2, int voffA) {
#pragma unroll
  for (int q = 0; q < 3; ++q) {
    if (q < C2 / 4) {
#pragma unroll
      for (int i = 0; i < 4; ++i) {
        int cc = 4 * q + i;
        if (cc < C1)
          ldA<M1>(av[q][i], voffA + cc * 2048, a1);
        else
          ldA<M2>(av[q][i], voffA + (cc - C1) * 2048, a2);
      }
    }
  }
}
template <int C1, int C2, int M1, int M2>
__device__ __forceinline__ void stream_run(bf16x8 av[3][4],
                                           const unsigned short* a1,
                                           const unsigned short* a2,
                                           const char* bg, int voffA, f32x16& acc) {
  constexpr int NP = C2 / 4;
  bf16x8 bb[2][4];
#pragma unroll
  for (int i = 0; i < 4; ++i) bb[0][i] = *(const bf16x8*)(bg + i * 1024);
#pragma unroll
  for (int ph = 0; ph < NP; ++ph) {
    if (ph + 1 < NP) {
#pragma unroll
      for (int i = 0; i < 4; ++i)
        bb[(ph + 1) & 1][i] = *(const bf16x8*)(bg + ((ph + 1) * 4 + i) * 1024);
    }
    if (ph < NP - 2) {
      WAITVM(8);
    } else if (ph == NP - 2) {
      WAITVM(4);
    } else {
      WAITVM(0);
    }
#pragma unroll
    for (int i = 0; i < 4; ++i)
      acc = __builtin_amdgcn_mfma_f32_32x32x16_bf16(av[ph % 3][i],
                                                    bb[ph & 1][i], acc, 0, 0, 0);
    if (ph + 3 < NP) {
#pragma unroll
      for (int i = 0; i < 4; ++i) {
        int cc = 4 * (ph + 3) + i;
        if (cc < C1)
          ldA<M1>(av[(ph + 3) % 3][i], voffA + cc * 2048, a1);
        else
          ldA<M2>(av[(ph + 3) % 3][i], voffA + (cc - C1) * 2048, a2);
      }
    }
  }
}

// ---------------- main persistent kernel ----------------
__global__ void __launch_bounds__(NT, 1)
lstm_main(const unsigned short* __restrict__ xfrag,
          const unsigned short* __restrict__ wf0,
          const unsigned short* __restrict__ wf1,
          const unsigned short* __restrict__ wf2,
          const unsigned short* __restrict__ wf3,
          const float* __restrict__ bias,
          unsigned short* __restrict__ hbuf,
          unsigned int* __restrict__ flags,
          float* __restrict__ out) {
  extern __shared__ char smem[];

  const int bid   = blockIdx.x;
  const int layer = bid >> 5;
  const int w     = bid & 31;
  const int tid   = threadIdx.x;
  const int lane  = tid & 63;
  const int wv    = tid >> 6;
  const int vm    = wv & 1;
  const int vn    = wv >> 1;
  const int C2r   = (layer == 0) ? 48 : 64;
  const int HOFF  = 2 * C2r * 64 * 16;

  const unsigned short* wfl =
      (layer == 0) ? wf0 : (layer == 1) ? wf1 : (layer == 2) ? wf2 : wf3;
  const unsigned short* wsl = wfl + (size_t)w * (2 * C2r * 64 * 8);

  for (int i = tid; i < 2 * C2r * 64; i += NT)
    *(f32x4*)(smem + (size_t)i * 16) = *(const f32x4*)(wsl + (size_t)i * 8);
  __syncthreads();

  const char* bg = smem + ((size_t)vn * C2r * 64 + lane) * 16;
  float* ztf = (float*)(smem + HOFF);

  const int pvm   = tid >> 6;          // epilogue mapping (tid<128)
  const int plane = tid & 63;
  const int eb    = pvm * 32 + (plane & 31);
  const int ehc8  = (plane >> 5) * 8;

  f32x4 bv4[4][2];
#pragma unroll
  for (int g = 0; g < 4; ++g) {
    const float* bp = bias + layer * 2048 + g * 512 + w * 16 + ehc8;
    bv4[g][0] = *(const f32x4*)bp;
    bv4[g][1] = *(const f32x4*)(bp + 4);
  }

  float creg[8];
#pragma unroll
  for (int r = 0; r < 8; ++r) creg[r] = 0.f;

  const int voffA = lane * 16 + vm * 1024;

  const unsigned short* hprev =
      (layer == 0) ? nullptr : (hbuf + (size_t)(layer - 1) * RING * 32768);
  const unsigned short* hself = hbuf + (size_t)layer * RING * 32768;

  const int zz    = vn * 32 + (lane & 31);
  const int rbase = vm * 32 + 4 * (lane >> 5);

  // ---- prologue: validate t=0 cross input (all waves), prefetch W(0) ----
  if (layer > 0) {
    while (true) {
      const unsigned* fp = (lane < 32) ? (flags + ((layer - 1) * 32 + lane) * 16)
                                       : flags;
      unsigned need = (lane < 32) ? 1u : 0u;
      unsigned v = ld_flag(fp);
      if (__ballot(need && v < need) == 0) break;
      __builtin_amdgcn_s_sleep(1);
    }
  }
  bf16x8 aw[24];
  if (layer == 0) {
#pragma unroll
    for (int c = 0; c < 16; ++c) ldA<0>(aw[c], voffA + c * 2048, xfrag);
  } else {
#pragma unroll
    for (int c = 0; c < 24; ++c) ldA<2>(aw[c], voffA + c * 2048, hprev);
  }
  wait_vm0();

  for (int t = 0; t < 512; ++t) {
    const unsigned short* aU = hself + (size_t)((t - 1) & (RING - 1)) * 32768;
    f32x16 acc = {};

    // ---- GEMM: stream-issue -> pure-reg W-GEMM -> stream ladder ----
    if (layer == 0) {
      if (t > 0) {
        bf16x8 av[3][4];
        stream_issue3<0, 32, 2, 2>(av, aU, aU, voffA);
        wgemm<16>(aw, bg, acc);
        stream_run<0, 32, 2, 2>(av, aU, aU, bg + 16 * 1024, voffA, acc);
      } else {
        wgemm<16>(aw, bg, acc);
      }
    } else {
      const unsigned short* aWr =
          hprev + (size_t)(t & (RING - 1)) * 32768 + 24 * 1024;
      if (t > 0) {
        bf16x8 av[3][4];
        stream_issue3<8, 40, 2, 2>(av, aWr, aU, voffA);
        wgemm<24>(aw, bg, acc);
        stream_run<8, 40, 2, 2>(av, aWr, aU, bg + 24 * 1024, voffA, acc);
      } else {
        bf16x8 av[3][4];
        stream_issue3<8, 8, 2, 2>(av, aWr, aWr, voffA);
        wgemm<24>(aw, bg, acc);
        stream_run<8, 8, 2, 2>(av, aWr, aWr, bg + 24 * 1024, voffA, acc);
      }
    }

    // ---- z -> LDS zt exchange ----
#pragma unroll
    for (int rg = 0; rg < 4; ++rg) {
      f32x4 v = {acc[4 * rg], acc[4 * rg + 1], acc[4 * rg + 2], acc[4 * rg + 3]};
      *(f32x4*)(ztf + zz * 68 + rbase + 8 * rg) = v;
    }
    __syncthreads();  // (a)

    // ---- gates (waves 0-1) || cross+ring polls (waves 2-3) ----
    float hreg[8], cnreg[8];
    bf16x8 hb;
    if (wv < 2) {
#pragma unroll
      for (int e = 0; e < 8; ++e) {
        int hc = ehc8 + e;
        float bf_ = (e < 4) ? bv4[0][0][e] : bv4[0][1][e - 4];
        float bi_ = (e < 4) ? bv4[1][0][e] : bv4[1][1][e - 4];
        float bo_ = (e < 4) ? bv4[2][0][e] : bv4[2][1][e - 4];
        float bg_ = (e < 4) ? bv4[3][0][e] : bv4[3][1][e - 4];
        float fg = sigmoid_fast(ztf[(0 + hc) * 68 + eb] + bf_);
        float ig = sigmoid_fast(ztf[(16 + hc) * 68 + eb] + bi_);
        float og = sigmoid_fast(ztf[(32 + hc) * 68 + eb] + bo_);
        float gg = tanh_fast(ztf[(48 + hc) * 68 + eb] + bg_);
        float cn = fg * creg[e] + ig * gg;
        creg[e] = cn;
        cnreg[e] = cn;
        float h = og * tanh_fast(cn);
        hreg[e] = h;
        hb[e] = (short)f2bf(h);
      }
    } else if (t < 511) {
      if (wv == 2) {
        // cross: h_prev(t+1) drained (layer>0)
        while (true) {
          const unsigned* fp = (layer > 0 && lane < 32)
                                   ? (flags + ((layer - 1) * 32 + lane) * 16)
                                   : flags;
          unsigned need = (layer > 0 && lane < 32) ? (unsigned)(t + 2) : 0u;
          unsigned v = ld_flag(fp);
          if (__ballot(need && v < need) == 0) break;
          __builtin_amdgcn_s_sleep(1);
        }
      } else {
        // ring credit for h(t+1) slot write
        while (true) {
          bool act = (layer < 3) && ((t + 1) >= RING) && (lane < 32);
          const unsigned* fp = act ? (flags + ((layer + 1) * 32 + lane) * 16)
                                   : flags;
          unsigned need = act ? (unsigned)(t + 2 - RING) : 0u;
          unsigned v = ld_flag(fp);
          if (__ballot(need && v < need) == 0) break;
          __builtin_amdgcn_s_sleep(1);
        }
      }
    }
    __builtin_amdgcn_s_barrier();  // (b): cross validated; zt reads done

    // ---- publish issue -> W(t+1) prefetch -> counted drain -> flag ----
    if (wv < 2) {
      unsigned short* dst = hbuf +
          ((size_t)layer * RING + (t & (RING - 1))) * 32768 +
          w * 1024 + pvm * 512 + plane * 8;
      st16_coh(dst, __builtin_bit_cast(f32x4, hb));
      if (layer == 3) {
        float* op = out + (size_t)eb * 262144 + (size_t)t * 512 + w * 16 + ehc8;
        f32x4 h0 = {hreg[0], hreg[1], hreg[2], hreg[3]};
        f32x4 h1 = {hreg[4], hreg[5], hreg[6], hreg[7]};
        *(f32x4*)op = h0;
        *(f32x4*)(op + 4) = h1;
      }
      if (t == 511) {
        float* hp = out + 16777216 + ((size_t)layer * 64 + eb) * 512 + w * 16 + ehc8;
        float* cp = hp + 131072;
        f32x4 h0 = {hreg[0], hreg[1], hreg[2], hreg[3]};
        f32x4 h1 = {hreg[4], hreg[5], hreg[6], hreg[7]};
        f32x4 c0 = {cnreg[0], cnreg[1], cnreg[2], cnreg[3]};
        f32x4 c1 = {cnreg[4], cnreg[5], cnreg[6], cnreg[7]};
        *(f32x4*)hp = h0;
        *(f32x4*)(hp + 4) = h1;
        *(f32x4*)cp = c0;
        *(f32x4*)(cp + 4) = c1;
      }
    }
    if (t < 511) {
      // W(t+1) prefetch (validated by wave2's cross-poll + (b))
      if (layer == 0) {
        const unsigned short* aWn = xfrag + (size_t)(t + 1) * 16384;
#pragma unroll
        for (int c = 0; c < 16; ++c) ldA<0>(aw[c], voffA + c * 2048, aWn);
      } else {
        const unsigned short* aWn =
            hprev + (size_t)((t + 1) & (RING - 1)) * 32768;
#pragma unroll
        for (int c = 0; c < 24; ++c) ldA<2>(aw[c], voffA + c * 2048, aWn);
      }
      WAITVM(24);  // drains h/out stores (older than the 24/16 W-loads)
    } else {
      wait_vm0();
    }
    __builtin_amdgcn_s_barrier();  // (c0): all h drained
    if (tid == 0)
      st4_coh(flags + (layer * 32 + w) * 16, (unsigned)(t + 1));

    // ---- self-poll (all waves): peers' h(t) drained ----
    if (t < 511) {
      while (true) {
        const unsigned* fp = (lane < 32) ? (flags + (layer * 32 + lane) * 16)
                                         : flags;
        unsigned need = (lane < 32) ? (unsigned)(t + 1) : 0u;
        unsigned v = ld_flag(fp);
        if (__ballot(need && v < need) == 0) break;
        __builtin_amdgcn_s_sleep(1);
      }
    }
    // ld_flag's vmcnt(0) also drained our W-prefetch: counter clean at loop top
  }
}

extern "C" void kernel_launch(void* const* d_in, const int* in_sizes, int n_in,
                              void* d_out, int out_size, void* d_ws, size_t ws_size,
                              hipStream_t stream) {
  const float* x = (const float*)d_in[0];
  const float *W[4], *U[4], *bw[4], *bu[4];
  for (int l = 0; l < 4; ++l) {
    W[l]  = (const float*)d_in[1 + 4 * l];
    U[l]  = (const float*)d_in[2 + 4 * l];
    bw[l] = (const float*)d_in[3 + 4 * l];
    bu[l] = (const float*)d_in[4 + 4 * l];
  }

  char* ws = (char*)d_ws;
  unsigned short* xfrag = (unsigned short*)(ws + 0);        // 16,777,216
  unsigned short* wfr0  = (unsigned short*)(ws + 16777216); //  3,145,728
  unsigned short* wfr1  = (unsigned short*)(ws + 19922944); //  4,194,304
  unsigned short* wfr2  = (unsigned short*)(ws + 24117248); //  4,194,304
  unsigned short* wfr3  = (unsigned short*)(ws + 28311552); //  4,194,304
  float*          biasp = (float*)(ws + 32505856);          //     32,768
  unsigned short* hbuf  = (unsigned short*)(ws + 32538624); //  2,097,152
  unsigned int*   flags = (unsigned int*)(ws + 34635776);   //      8,192
  float* out = (float*)d_out;

  cvt_x_kernel<<<4096, 256, 0, stream>>>(x, xfrag);
  cvt_w_kernel<<<768, 256, 0, stream>>>(W[0], U[0], wfr0, 48, 256);
  cvt_w_kernel<<<1024, 256, 0, stream>>>(W[1], U[1], wfr1, 64, 512);
  cvt_w_kernel<<<1024, 256, 0, stream>>>(W[2], U[2], wfr2, 64, 512);
  cvt_w_kernel<<<1024, 256, 0, stream>>>(W[3], U[3], wfr3, 64, 512);
  bias_kernel<<<8, 256, 0, stream>>>(bw[0], bu[0], biasp + 0 * 2048);
  bias_kernel<<<8, 256, 0, stream>>>(bw[1], bu[1], biasp + 1 * 2048);
  bias_kernel<<<8, 256, 0, stream>>>(bw[2], bu[2], biasp + 2 * 2048);
  bias_kernel<<<8, 256, 0, stream>>>(bw[3], bu[3], biasp + 3 * 2048);
  zero_flags<<<8, 256, 0, stream>>>(flags);

  hipFuncSetAttribute((const void*)lstm_main,
                      hipFuncAttributeMaxDynamicSharedMemorySize, 148480);
  lstm_main<<<dim3(4 * WPL), dim3(NT), 148480, stream>>>(
      xfrag, wfr0, wfr1, wfr2, wfr3, biasp, hbuf, flags, out);
}

// Round 13
// 2395.356 us; speedup vs baseline: 1.1292x; 1.1292x over previous
//
#include <hip/hip_runtime.h>

typedef __attribute__((ext_vector_type(8))) short bf16x8;
typedef __attribute__((ext_vector_type(4))) float f32x4;

// B=64, T=512, D=256, H=512, L=4, 4H=2048
// 32 wgs/layer (16 hcols), 256 thr = 4 waves. Grid 128. v9 structure+layouts
// (verified). v13: full-issue U (16 loads in flight) + W kept in registers
// across the step (prefetched under the self-poll) + poll/publish overlap.
#define WPL 32
#define NT 256
#define RING 8

__device__ __forceinline__ unsigned short f2bf(float f) {
  unsigned int u = __float_as_uint(f);
  u += 0x7FFFu + ((u >> 16) & 1u);
  return (unsigned short)(u >> 16);
}
__device__ __forceinline__ float sigmoid_fast(float x) {
  return __builtin_amdgcn_rcpf(1.0f + __builtin_amdgcn_exp2f(-1.4426950408889634f * x));
}
__device__ __forceinline__ float tanh_fast(float x) {
  return 1.0f - 2.0f * __builtin_amdgcn_rcpf(
                           1.0f + __builtin_amdgcn_exp2f(2.885390081777927f * x));
}
__device__ __forceinline__ void wait_vm0() {
  asm volatile("s_waitcnt vmcnt(0)" ::: "memory");
  __builtin_amdgcn_sched_barrier(0);
}
#define WAITVM(N)                                         \
  do {                                                    \
    asm volatile("s_waitcnt vmcnt(" #N ")" ::: "memory"); \
    __builtin_amdgcn_sched_barrier(0);                    \
  } while (0)

template <int MODE>  // 0 = cached (x), 2 = sc0 sc1 (LLC coherent h)
__device__ __forceinline__ void ldA(bf16x8& d, int voff, const unsigned short* base) {
  if constexpr (MODE == 0)
    asm volatile("global_load_dwordx4 %0, %1, %2"
                 : "=v"(d) : "v"(voff), "s"(base));
  else
    asm volatile("global_load_dwordx4 %0, %1, %2 sc0 sc1"
                 : "=v"(d) : "v"(voff), "s"(base));
}
__device__ __forceinline__ unsigned ld_flag(const unsigned* p) {
  unsigned v;
  asm volatile("global_load_dword %0, %1, off sc0 sc1\n\ts_waitcnt vmcnt(0)"
               : "=v"(v) : "v"(p) : "memory");
  return v;
}
__device__ __forceinline__ void st16_coh(void* p, f32x4 v) {
  asm volatile("global_store_dwordx4 %0, %1, off sc0 sc1" :: "v"(p), "v"(v) : "memory");
}
__device__ __forceinline__ void st4_coh(void* p, unsigned v) {
  asm volatile("global_store_dword %0, %1, off sc0 sc1" :: "v"(p), "v"(v) : "memory");
}

// ---------------- prep kernels (v9, verified) ----------------

// x [B,T,D] f32 -> xfrag [T][c(8)][bt(4)][lane(64)][e(8)] bf16, lane-linear
__global__ void cvt_x_kernel(const float* __restrict__ x,
                             unsigned short* __restrict__ xf) {
  int tid = blockIdx.x * 256 + threadIdx.x;  // 1,048,576
  int t     = tid >> 11;
  int inner = tid & 2047;
  int lane  = inner & 63;
  int bt    = (inner >> 6) & 3;
  int c     = inner >> 8;
  int b = bt * 16 + (lane & 15);
  int d = c * 32 + (lane >> 4) * 8;
  const float* s = x + ((size_t)b * 512 + t) * 256 + d;
  f32x4 v0 = *(const f32x4*)s;
  f32x4 v1 = *(const f32x4*)(s + 4);
  bf16x8 o;
  o[0] = (short)f2bf(v0[0]); o[1] = (short)f2bf(v0[1]);
  o[2] = (short)f2bf(v0[2]); o[3] = (short)f2bf(v0[3]);
  o[4] = (short)f2bf(v1[0]); o[5] = (short)f2bf(v1[1]);
  o[6] = (short)f2bf(v1[2]); o[7] = (short)f2bf(v1[3]);
  *(bf16x8*)(xf + (size_t)t * 16384 + (size_t)inner * 8) = o;
}

// W/U f32 -> wfrag [w(32)][g(4)][c(C2)][lane(64)][e(8)] bf16
__global__ void cvt_w_kernel(const float* __restrict__ W,
                             const float* __restrict__ U,
                             unsigned short* __restrict__ dst,
                             int C2, int split) {
  int tid = blockIdx.x * 256 + threadIdx.x;
  int lane = tid & 63;
  int c    = (tid >> 6) % C2;
  int rest = tid / (64 * C2);
  int g = rest & 3;
  int w = rest >> 2;
  int row = g * 512 + w * 16 + (lane & 15);
  int k   = c * 32 + (lane >> 4) * 8;
  const float* s = (k < split) ? (W + (size_t)row * split + k)
                               : (U + (size_t)row * 512 + (k - split));
  f32x4 v0 = *(const f32x4*)s;
  f32x4 v1 = *(const f32x4*)(s + 4);
  bf16x8 o;
  o[0] = (short)f2bf(v0[0]); o[1] = (short)f2bf(v0[1]);
  o[2] = (short)f2bf(v0[2]); o[3] = (short)f2bf(v0[3]);
  o[4] = (short)f2bf(v1[0]); o[5] = (short)f2bf(v1[1]);
  o[6] = (short)f2bf(v1[2]); o[7] = (short)f2bf(v1[3]);
  *(bf16x8*)(dst + (size_t)tid * 8) = o;
}

__global__ void bias_kernel(const float* __restrict__ bw,
                            const float* __restrict__ bu,
                            float* __restrict__ dst) {
  int i = blockIdx.x * 256 + threadIdx.x;  // 2048
  dst[i] = bw[i] + bu[i];
}

__global__ void zero_flags(unsigned int* __restrict__ p) {
  int i = blockIdx.x * 256 + threadIdx.x;  // 2048
  p[i] = 0u;
}

// ---------------- main persistent kernel ----------------
// grid 128: layer = bid>>5, w = bid&31 (hcols w*16..+16).
// 4 waves: wave vm owns m-tile rows vm*16..+16, full K, 4 gates in acc[4].
__global__ void __launch_bounds__(NT, 1)
lstm_main(const unsigned short* __restrict__ xfrag,
          const unsigned short* __restrict__ wf0,
          const unsigned short* __restrict__ wf1,
          const unsigned short* __restrict__ wf2,
          const unsigned short* __restrict__ wf3,
          const float* __restrict__ bias,
          unsigned short* __restrict__ hbuf,
          unsigned int* __restrict__ flags,
          float* __restrict__ out) {
  extern __shared__ char smem[];

  const int bid   = blockIdx.x;
  const int layer = bid >> 5;
  const int w     = bid & 31;
  const int tid   = threadIdx.x;
  const int lane  = tid & 63;
  const int wv    = tid >> 6;
  const int vm    = wv;           // m-tile (16 rows) per wave
  const int l15   = lane & 15;
  const int lhi   = lane >> 4;
  const int hcol  = w * 16 + l15;
  const int C2r   = (layer == 0) ? 24 : 32;
  const int HOFF  = 4 * C2r * 64 * 16;  // LDS h-transpose buffer offset

  const unsigned short* wfl =
      (layer == 0) ? wf0 : (layer == 1) ? wf1 : (layer == 2) ? wf2 : wf3;
  const unsigned short* wsl = wfl + (size_t)w * (4 * C2r * 64 * 8);

  // stage weights into LDS (frag-linear; one-time)
  for (int i = tid; i < 4 * C2r * 64; i += NT)
    *(f32x4*)(smem + (size_t)i * 16) = *(const f32x4*)(wsl + (size_t)i * 8);
  __syncthreads();

  const char* bg[4];
#pragma unroll
  for (int g = 0; g < 4; ++g) bg[g] = smem + ((size_t)g * C2r * 64 + lane) * 16;

  float bv[4];
#pragma unroll
  for (int g = 0; g < 4; ++g) bv[g] = bias[layer * 2048 + g * 512 + hcol];

  float creg[4];
#pragma unroll
  for (int r = 0; r < 4; ++r) creg[r] = 0.f;

  const int voffA = lane * 16 + vm * 1024;
  const int base_w = (w >> 1) * 2048 + (w & 1) * 256;  // shorts

  const unsigned short* hprev =
      (layer == 0) ? nullptr : (hbuf + (size_t)(layer - 1) * RING * 32768);
  const unsigned short* hself = hbuf + (size_t)layer * RING * 32768;

  // h publish store thread mapping (tid < 128)
  const int sb_bt = tid >> 5;
  const int sb_q  = (tid >> 4) & 1;
  const int sb_bl = tid & 15;
  const int slot_off = base_w + sb_bt * 512 + sb_q * 128 + sb_bl * 8;

  // ---- prologue: validate + prefetch W(0) into registers ----
  bf16x8 aw[16];
  if (layer > 0) {
    while (true) {
      const unsigned* fp = (lane < 32) ? (flags + ((layer - 1) * 32 + lane) * 16)
                                       : flags;
      unsigned need = (lane < 32) ? 1u : 0u;
      unsigned v = ld_flag(fp);
      if (__ballot(need && v < need) == 0) break;
      __builtin_amdgcn_s_sleep(1);
    }
#pragma unroll
    for (int c = 0; c < 16; ++c) ldA<2>(aw[c], voffA + c * 4096, hprev);
  } else {
#pragma unroll
    for (int c = 0; c < 8; ++c) ldA<0>(aw[c], voffA + c * 4096, xfrag);
  }
  wait_vm0();

  for (int t = 0; t < 512; ++t) {
    f32x4 acc[4];
    const f32x4 z4 = {0.f, 0.f, 0.f, 0.f};
#pragma unroll
    for (int g = 0; g < 4; ++g) acc[g] = z4;

    // ---- full-issue U loads (validated by self-poll last iteration) ----
    bf16x8 av[16];
    if (t > 0) {
      const unsigned short* aU = hself + (size_t)((t - 1) & (RING - 1)) * 32768;
#pragma unroll
      for (int c = 0; c < 16; ++c) ldA<2>(av[c], voffA + c * 4096, aU);
    }

    // ---- W-GEMM from registers (U loads flying underneath) ----
    if (layer == 0) {
#pragma unroll
      for (int c = 0; c < 8; ++c)
#pragma unroll
        for (int g = 0; g < 4; ++g)
          acc[g] = __builtin_amdgcn_mfma_f32_16x16x32_bf16(
              aw[c], *(const bf16x8*)(bg[g] + c * 1024), acc[g], 0, 0, 0);
    } else {
#pragma unroll
      for (int c = 0; c < 16; ++c)
#pragma unroll
        for (int g = 0; g < 4; ++g)
          acc[g] = __builtin_amdgcn_mfma_f32_16x16x32_bf16(
              aw[c], *(const bf16x8*)(bg[g] + c * 1024), acc[g], 0, 0, 0);
    }

    // ---- U-GEMM ladder: consume as they arrive ----
    if (t > 0) {
      const int c0 = (layer == 0) ? 8 : 16;
      WAITVM(12);
#pragma unroll
      for (int c = 0; c < 4; ++c)
#pragma unroll
        for (int g = 0; g < 4; ++g)
          acc[g] = __builtin_amdgcn_mfma_f32_16x16x32_bf16(
              av[c], *(const bf16x8*)(bg[g] + (c0 + c) * 1024), acc[g], 0, 0, 0);
      WAITVM(8);
#pragma unroll
      for (int c = 4; c < 8; ++c)
#pragma unroll
        for (int g = 0; g < 4; ++g)
          acc[g] = __builtin_amdgcn_mfma_f32_16x16x32_bf16(
              av[c], *(const bf16x8*)(bg[g] + (c0 + c) * 1024), acc[g], 0, 0, 0);
      WAITVM(4);
#pragma unroll
      for (int c = 8; c < 12; ++c)
#pragma unroll
        for (int g = 0; g < 4; ++g)
          acc[g] = __builtin_amdgcn_mfma_f32_16x16x32_bf16(
              av[c], *(const bf16x8*)(bg[g] + (c0 + c) * 1024), acc[g], 0, 0, 0);
      WAITVM(0);
#pragma unroll
      for (int c = 12; c < 16; ++c)
#pragma unroll
        for (int g = 0; g < 4; ++g)
          acc[g] = __builtin_amdgcn_mfma_f32_16x16x32_bf16(
              av[c], *(const bf16x8*)(bg[g] + (c0 + c) * 1024), acc[g], 0, 0, 0);
    }

    // ---- gates + state; h -> LDS transpose ----
    float hreg[4], cnreg[4];
#pragma unroll
    for (int r = 0; r < 4; ++r) {
      float fg = sigmoid_fast(acc[0][r] + bv[0]);
      float ig = sigmoid_fast(acc[1][r] + bv[1]);
      float og = sigmoid_fast(acc[2][r] + bv[2]);
      float gg = tanh_fast(acc[3][r] + bv[3]);
      float cn = fg * creg[r] + ig * gg;
      creg[r] = cn;
      cnreg[r] = cn;
      float h = og * tanh_fast(cn);
      hreg[r] = h;
      *(unsigned short*)(smem + HOFF + (vm * 16 + lhi * 4 + r) * 32 + l15 * 2) =
          f2bf(h);
    }
    __syncthreads();

    // ---- publish (waves 0-1) || cross-poll (wave 2) || ring-poll (wave 3) ----
    if (wv < 2) {
      f32x4 hv = *(const f32x4*)(smem + HOFF + (sb_bt * 16 + sb_bl) * 32 + sb_q * 16);
      unsigned short* dst = hbuf +
          ((size_t)layer * RING + (t & (RING - 1))) * 32768 + slot_off;
      st16_coh(dst, hv);
      wait_vm0();
    } else if (wv == 2) {
      if (t < 511 && layer > 0) {
        while (true) {
          const unsigned* fp = (lane < 32)
                                   ? (flags + ((layer - 1) * 32 + lane) * 16)
                                   : flags;
          unsigned need = (lane < 32) ? (unsigned)(t + 2) : 0u;
          unsigned v = ld_flag(fp);
          if (__ballot(need && v < need) == 0) break;
          __builtin_amdgcn_s_sleep(1);
        }
      }
    } else {
      if (t < 511 && layer < 3 && (t + 1) >= RING) {
        while (true) {
          const unsigned* fp = (lane < 32)
                                   ? (flags + ((layer + 1) * 32 + lane) * 16)
                                   : flags;
          unsigned need = (lane < 32) ? (unsigned)(t + 2 - RING) : 0u;
          unsigned v = ld_flag(fp);
          if (__ballot(need && v < need) == 0) break;
          __builtin_amdgcn_s_sleep(1);
        }
      }
    }
    __syncthreads();  // publish drained + t+1 inputs/credit validated
    if (tid == 0)
      st4_coh(flags + (layer * 32 + w) * 16, (unsigned)(t + 1));

    // ---- output stores (drained later by poll/final) ----
    if (layer == 3) {
#pragma unroll
      for (int r = 0; r < 4; ++r) {
        int bidx = vm * 16 + lhi * 4 + r;
        out[(size_t)bidx * 262144 + (size_t)t * 512 + hcol] = hreg[r];
      }
    }
    if (t == 511) {
#pragma unroll
      for (int r = 0; r < 4; ++r) {
        int bidx = vm * 16 + lhi * 4 + r;
        out[16777216 + ((size_t)layer * 64 + bidx) * 512 + hcol] = hreg[r];
        out[16777216 + 131072 + ((size_t)layer * 64 + bidx) * 512 + hcol] = cnreg[r];
      }
    }

    if (t < 511) {
      // ---- W(t+1) prefetch (cross validated by wave2 + barrier) ----
      if (layer == 0) {
        const unsigned short* aWn = xfrag + (size_t)(t + 1) * 16384;
#pragma unroll
        for (int c = 0; c < 8; ++c) ldA<0>(aw[c], voffA + c * 4096, aWn);
      } else {
        const unsigned short* aWn =
            hprev + (size_t)((t + 1) & (RING - 1)) * 32768;
#pragma unroll
        for (int c = 0; c < 16; ++c) ldA<2>(aw[c], voffA + c * 4096, aWn);
      }
      // ---- self-poll (all waves); ld_flag's vmcnt(0) drains W prefetch ----
      while (true) {
        const unsigned* fp = (lane < 32) ? (flags + (layer * 32 + lane) * 16)
                                         : flags;
        unsigned need = (lane < 32) ? (unsigned)(t + 1) : 0u;
        unsigned v = ld_flag(fp);
        if (__ballot(need && v < need) == 0) break;
        __builtin_amdgcn_s_sleep(1);
      }
    }
  }
  wait_vm0();
}

extern "C" void kernel_launch(void* const* d_in, const int* in_sizes, int n_in,
                              void* d_out, int out_size, void* d_ws, size_t ws_size,
                              hipStream_t stream) {
  const float* x = (const float*)d_in[0];
  const float *W[4], *U[4], *bw[4], *bu[4];
  for (int l = 0; l < 4; ++l) {
    W[l]  = (const float*)d_in[1 + 4 * l];
    U[l]  = (const float*)d_in[2 + 4 * l];
    bw[l] = (const float*)d_in[3 + 4 * l];
    bu[l] = (const float*)d_in[4 + 4 * l];
  }

  char* ws = (char*)d_ws;
  unsigned short* xfrag = (unsigned short*)(ws + 0);        // 16,777,216
  unsigned short* wfr0  = (unsigned short*)(ws + 16777216); //  3,145,728
  unsigned short* wfr1  = (unsigned short*)(ws + 19922944); //  4,194,304
  unsigned short* wfr2  = (unsigned short*)(ws + 24117248); //  4,194,304
  unsigned short* wfr3  = (unsigned short*)(ws + 28311552); //  4,194,304
  float*          biasp = (float*)(ws + 32505856);          //     32,768
  unsigned short* hbuf  = (unsigned short*)(ws + 32538624); //  2,097,152
  unsigned int*   flags = (unsigned int*)(ws + 34635776);   //      8,192
  float* out = (float*)d_out;

  cvt_x_kernel<<<4096, 256, 0, stream>>>(x, xfrag);
  cvt_w_kernel<<<768, 256, 0, stream>>>(W[0], U[0], wfr0, 24, 256);
  cvt_w_kernel<<<1024, 256, 0, stream>>>(W[1], U[1], wfr1, 32, 512);
  cvt_w_kernel<<<1024, 256, 0, stream>>>(W[2], U[2], wfr2, 32, 512);
  cvt_w_kernel<<<1024, 256, 0, stream>>>(W[3], U[3], wfr3, 32, 512);
  bias_kernel<<<8, 256, 0, stream>>>(bw[0], bu[0], biasp + 0 * 2048);
  bias_kernel<<<8, 256, 0, stream>>>(bw[1], bu[1], biasp + 1 * 2048);
  bias_kernel<<<8, 256, 0, stream>>>(bw[2], bu[2], biasp + 2 * 2048);
  bias_kernel<<<8, 256, 0, stream>>>(bw[3], bu[3], biasp + 3 * 2048);
  zero_flags<<<8, 256, 0, stream>>>(flags);

  hipFuncSetAttribute((const void*)lstm_main,
                      hipFuncAttributeMaxDynamicSharedMemorySize, 135168);
  lstm_main<<<dim3(4 * WPL), dim3(NT), 135168, stream>>>(
      xfrag, wfr0, wfr1, wfr2, wfr3, biasp, hbuf, flags, out);
}

// Round 14
// 2069.860 us; speedup vs baseline: 1.3067x; 1.1573x over previous
//
#include <hip/hip_runtime.h>

typedef __attribute__((ext_vector_type(8))) short bf16x8;
typedef __attribute__((ext_vector_type(4))) float f32x4;

// B=64, T=512, D=256, H=512, L=4, 4H=2048
// 32 wgs per layer (16 hcols each), 256 threads (4 waves) per wg. Grid 128.
// v15 = round-9 kernel EXACTLY, with one isolated change: A-pipeline depth
// 3 -> 6 (24 loads in flight) in gemm_run. Everything else byte-identical.
#define WPL 32
#define NT 256
#define RING 8

__device__ __forceinline__ unsigned short f2bf(float f) {
  unsigned int u = __float_as_uint(f);
  u += 0x7FFFu + ((u >> 16) & 1u);
  return (unsigned short)(u >> 16);
}
__device__ __forceinline__ float sigmoid_fast(float x) {
  return __builtin_amdgcn_rcpf(1.0f + __builtin_amdgcn_exp2f(-1.4426950408889634f * x));
}
__device__ __forceinline__ float tanh_fast(float x) {
  return 1.0f - 2.0f * __builtin_amdgcn_rcpf(
                           1.0f + __builtin_amdgcn_exp2f(2.885390081777927f * x));
}
__device__ __forceinline__ void wait_vm0() {
  asm volatile("s_waitcnt vmcnt(0)" ::: "memory");
  __builtin_amdgcn_sched_barrier(0);
}
#define WAITVM(N)                                         \
  do {                                                    \
    asm volatile("s_waitcnt vmcnt(" #N ")" ::: "memory"); \
    __builtin_amdgcn_sched_barrier(0);                    \
  } while (0)

// MODE: 0 = plain cached (read-only x), 2 = sc0 sc1 (LLC coherent h)
template <int MODE>
__device__ __forceinline__ void ldA(bf16x8& d, int voff, const unsigned short* base) {
  if constexpr (MODE == 0)
    asm volatile("global_load_dwordx4 %0, %1, %2"
                 : "=v"(d) : "v"(voff), "s"(base));
  else
    asm volatile("global_load_dwordx4 %0, %1, %2 sc0 sc1"
                 : "=v"(d) : "v"(voff), "s"(base));
}
__device__ __forceinline__ unsigned ld_flag(const unsigned* p) {
  unsigned v;
  asm volatile("global_load_dword %0, %1, off sc0 sc1\n\ts_waitcnt vmcnt(0)"
               : "=v"(v) : "v"(p) : "memory");
  return v;
}
__device__ __forceinline__ void st16_coh(void* p, f32x4 v) {
  asm volatile("global_store_dwordx4 %0, %1, off sc0 sc1" :: "v"(p), "v"(v) : "memory");
}
__device__ __forceinline__ void st4_coh(void* p, unsigned v) {
  asm volatile("global_store_dword %0, %1, off sc0 sc1" :: "v"(p), "v"(v) : "memory");
}

// ---------------- prep kernels ----------------

// x [B,T,D] f32 -> xfrag [T][c(8)][bt(4)][lane(64)][e(8)] bf16, lane-linear
__global__ void cvt_x_kernel(const float* __restrict__ x,
                             unsigned short* __restrict__ xf) {
  int tid = blockIdx.x * 256 + threadIdx.x;  // 1,048,576
  int t     = tid >> 11;
  int inner = tid & 2047;
  int lane  = inner & 63;
  int bt    = (inner >> 6) & 3;
  int c     = inner >> 8;
  int b = bt * 16 + (lane & 15);
  int d = c * 32 + (lane >> 4) * 8;
  const float* s = x + ((size_t)b * 512 + t) * 256 + d;
  f32x4 v0 = *(const f32x4*)s;
  f32x4 v1 = *(const f32x4*)(s + 4);
  bf16x8 o;
  o[0] = (short)f2bf(v0[0]); o[1] = (short)f2bf(v0[1]);
  o[2] = (short)f2bf(v0[2]); o[3] = (short)f2bf(v0[3]);
  o[4] = (short)f2bf(v1[0]); o[5] = (short)f2bf(v1[1]);
  o[6] = (short)f2bf(v1[2]); o[7] = (short)f2bf(v1[3]);
  *(bf16x8*)(xf + (size_t)t * 16384 + (size_t)inner * 8) = o;
}

// W/U f32 -> wfrag [w(32)][g(4)][c(C2)][lane(64)][e(8)] bf16
__global__ void cvt_w_kernel(const float* __restrict__ W,
                             const float* __restrict__ U,
                             unsigned short* __restrict__ dst,
                             int C2, int split) {
  int tid = blockIdx.x * 256 + threadIdx.x;
  int lane = tid & 63;
  int c    = (tid >> 6) % C2;
  int rest = tid / (64 * C2);
  int g = rest & 3;
  int w = rest >> 2;
  int row = g * 512 + w * 16 + (lane & 15);
  int k   = c * 32 + (lane >> 4) * 8;
  const float* s = (k < split) ? (W + (size_t)row * split + k)
                               : (U + (size_t)row * 512 + (k - split));
  f32x4 v0 = *(const f32x4*)s;
  f32x4 v1 = *(const f32x4*)(s + 4);
  bf16x8 o;
  o[0] = (short)f2bf(v0[0]); o[1] = (short)f2bf(v0[1]);
  o[2] = (short)f2bf(v0[2]); o[3] = (short)f2bf(v0[3]);
  o[4] = (short)f2bf(v1[0]); o[5] = (short)f2bf(v1[1]);
  o[6] = (short)f2bf(v1[2]); o[7] = (short)f2bf(v1[3]);
  *(bf16x8*)(dst + (size_t)tid * 8) = o;
}

__global__ void bias_kernel(const float* __restrict__ bw,
                            const float* __restrict__ bu,
                            float* __restrict__ dst) {
  int i = blockIdx.x * 256 + threadIdx.x;  // 2048
  dst[i] = bw[i] + bu[i];
}

__global__ void zero_flags(unsigned int* __restrict__ p) {
  int i = blockIdx.x * 256 + threadIdx.x;  // 2048
  p[i] = 0u;
}

// ---------------- pipelined merged GEMM (C2 chunks over two bases) ----------------
// A from global frag layout; B from LDS frag layout. 6-phase-deep A pipeline,
// counted vmcnt (4 loads/phase); double-buffered B. Requires vmcnt==0 at
// entry; leaves vmcnt==0 at exit.
template <int C1, int C2, int M1, int M2>
__device__ __forceinline__ void gemm_run(const unsigned short* __restrict__ a1,
                                         const unsigned short* __restrict__ a2,
                                         const char* bg0, const char* bg1,
                                         const char* bg2, const char* bg3,
                                         int voffA, f32x4 acc[4]) {
  constexpr int NP = C2 / 4;
  bf16x8 av[6][4];
  bf16x8 bb[2][4][4];
  const char* bgp[4] = {bg0, bg1, bg2, bg3};

  auto issueA_iter = [&](int cc, int s6, int i) {
    if (cc < C1)
      ldA<M1>(av[s6][i], voffA + cc * 4096, a1);
    else
      ldA<M2>(av[s6][i], voffA + (cc - C1) * 4096, a2);
  };
  auto issueA_phase = [&](int q) {
#pragma unroll
    for (int i = 0; i < 4; ++i) issueA_iter(4 * q + i, q % 6, i);
  };
  auto loadB_phase = [&](int q) {
#pragma unroll
    for (int i = 0; i < 4; ++i)
#pragma unroll
      for (int g = 0; g < 4; ++g)
        bb[q & 1][i][g] = *(const bf16x8*)(bgp[g] + (4 * q + i) * 1024);
  };

#pragma unroll
  for (int q = 0; q < 6; ++q)
    if (q < NP) issueA_phase(q);
  loadB_phase(0);

#pragma unroll
  for (int ph = 0; ph < NP; ++ph) {
    if (ph + 1 < NP) loadB_phase(ph + 1);
    {
      // outstanding = min(NP, ph+6)*4 issued − (ph)*4 completed;
      // need phase ph's 4 done → wait to (min(NP, ph+6) − (ph+1)) * 4
      const int nw = (((NP < ph + 6) ? NP : ph + 6) - (ph + 1)) * 4;
      if (nw >= 20) {
        WAITVM(20);
      } else if (nw == 16) {
        WAITVM(16);
      } else if (nw == 12) {
        WAITVM(12);
      } else if (nw == 8) {
        WAITVM(8);
      } else if (nw == 4) {
        WAITVM(4);
      } else {
        WAITVM(0);
      }
    }
#pragma unroll
    for (int i = 0; i < 4; ++i)
#pragma unroll
      for (int g = 0; g < 4; ++g)
        acc[g] = __builtin_amdgcn_mfma_f32_16x16x32_bf16(av[ph % 6][i],
                                                         bb[ph & 1][i][g],
                                                         acc[g], 0, 0, 0);
    if (ph + 6 < NP) issueA_phase(ph + 6);
  }
}

// ---------------- main persistent kernel ----------------
// grid 128: layer = bid>>5, w = bid&31 (hcols w*16..+16).
// 4 waves: wave vm owns m-tile rows vm*16..+16, full K.
__global__ void __launch_bounds__(NT, 1)
lstm_main(const unsigned short* __restrict__ xfrag,
          const unsigned short* __restrict__ wf0,
          const unsigned short* __restrict__ wf1,
          const unsigned short* __restrict__ wf2,
          const unsigned short* __restrict__ wf3,
          const float* __restrict__ bias,
          unsigned short* __restrict__ hbuf,
          unsigned int* __restrict__ flags,
          float* __restrict__ out) {
  extern __shared__ char smem[];

  const int bid   = blockIdx.x;
  const int layer = bid >> 5;
  const int w     = bid & 31;
  const int tid   = threadIdx.x;
  const int lane  = tid & 63;
  const int vm    = tid >> 6;
  const int l15   = lane & 15;
  const int lhi   = lane >> 4;
  const int hcol  = w * 16 + l15;
  const int C2r   = (layer == 0) ? 24 : 32;
  const int HOFF  = 4 * C2r * 64 * 16;  // LDS h-transpose buffer offset

  const unsigned short* wfl =
      (layer == 0) ? wf0 : (layer == 1) ? wf1 : (layer == 2) ? wf2 : wf3;
  const unsigned short* wsl = wfl + (size_t)w * (4 * C2r * 64 * 8);

  // stage weights into LDS (frag-linear; one-time)
  for (int i = tid; i < 4 * C2r * 64; i += NT)
    *(f32x4*)(smem + (size_t)i * 16) = *(const f32x4*)(wsl + (size_t)i * 8);
  __syncthreads();

  const char* bg[4];
#pragma unroll
  for (int g = 0; g < 4; ++g) bg[g] = smem + ((size_t)g * C2r * 64 + lane) * 16;

  float bv[4];
#pragma unroll
  for (int g = 0; g < 4; ++g) bv[g] = bias[layer * 2048 + g * 512 + hcol];

  float creg[4];
#pragma unroll
  for (int r = 0; r < 4; ++r) creg[r] = 0.f;

  const int voffA = lane * 16 + vm * 1024;
  const int base_w = (w >> 1) * 2048 + (w & 1) * 256;  // shorts

  const unsigned short* hprev =
      (layer == 0) ? nullptr : (hbuf + (size_t)(layer - 1) * RING * 32768);
  const unsigned short* hself = hbuf + (size_t)layer * RING * 32768;

  // h publish store thread mapping (tid < 128)
  const int sb_bt = tid >> 5;
  const int sb_q  = (tid >> 4) & 1;
  const int sb_bl = tid & 15;
  const int slot_off = base_w + sb_bt * 512 + sb_q * 128 + sb_bl * 8;

  // ---- prologue poll: validate t=0 cross input (h_prev(0)) ----
  if (layer > 0 && vm == 0) {
    const unsigned* fp = flags;
    unsigned need = 0;
    if (lane < 32) {
      fp = flags + ((layer - 1) * 32 + lane) * 16;
      need = 1u;
    }
    while (true) {
      unsigned v = need ? ld_flag(fp) : 0u;
      if (__ballot(need && v < need) == 0) break;
      __builtin_amdgcn_s_sleep(1);
    }
  }
  __syncthreads();
  wait_vm0();  // staging/bias/poll drained: vmcnt==0 for the counted ladder

  for (int t = 0; t < 512; ++t) {
    // ---- merged pipelined GEMM (inputs validated by prior polls) ----
    const unsigned short* aW =
        (layer == 0) ? (xfrag + (size_t)t * 16384)
                     : (hprev + (size_t)(t & (RING - 1)) * 32768);
    const unsigned short* aU =
        hself + (size_t)((t - 1) & (RING - 1)) * 32768;

    f32x4 acc[4];
    const f32x4 z4 = {0.f, 0.f, 0.f, 0.f};
#pragma unroll
    for (int g = 0; g < 4; ++g) acc[g] = z4;

    if (t == 0) {
      if (layer == 0)
        gemm_run<8, 8, 0, 0>(aW, aW, bg[0], bg[1], bg[2], bg[3], voffA, acc);
      else
        gemm_run<16, 16, 2, 2>(aW, aW, bg[0], bg[1], bg[2], bg[3], voffA, acc);
    } else {
      if (layer == 0)
        gemm_run<8, 24, 0, 2>(aW, aU, bg[0], bg[1], bg[2], bg[3], voffA, acc);
      else
        gemm_run<16, 32, 2, 2>(aW, aU, bg[0], bg[1], bg[2], bg[3], voffA, acc);
    }

    // ---- gates + state; h -> LDS transpose ----
    float hreg[4], cnreg[4];
#pragma unroll
    for (int r = 0; r < 4; ++r) {
      float fg = sigmoid_fast(acc[0][r] + bv[0]);
      float ig = sigmoid_fast(acc[1][r] + bv[1]);
      float og = sigmoid_fast(acc[2][r] + bv[2]);
      float gg = tanh_fast(acc[3][r] + bv[3]);
      float cn = fg * creg[r] + ig * gg;
      creg[r] = cn;
      cnreg[r] = cn;
      float h = og * tanh_fast(cn);
      hreg[r] = h;
      *(unsigned short*)(smem + HOFF + (vm * 16 + lhi * 4 + r) * 32 + l15 * 2) =
          f2bf(h);
    }
    __syncthreads();

    // ---- coalesced coherent h publish (threads 0..127) ----
    if (tid < 128) {
      f32x4 hv = *(const f32x4*)(smem + HOFF + (sb_bt * 16 + sb_bl) * 32 + sb_q * 16);
      unsigned short* dst = hbuf +
          ((size_t)layer * RING + (t & (RING - 1))) * 32768 + slot_off;
      st16_coh(dst, hv);
      wait_vm0();
    }
    __syncthreads();
    if (tid == 0)
      st4_coh(flags + (layer * 32 + w) * 16, (unsigned)(t + 1));

    // ---- output stores (overlap the end-polls below) ----
    if (layer == 3) {
#pragma unroll
      for (int r = 0; r < 4; ++r) {
        int bidx = vm * 16 + lhi * 4 + r;
        out[(size_t)bidx * 262144 + (size_t)t * 512 + hcol] = hreg[r];
      }
    }
    if (t == 511) {
#pragma unroll
      for (int r = 0; r < 4; ++r) {
        int bidx = vm * 16 + lhi * 4 + r;
        out[16777216 + ((size_t)layer * 64 + bidx) * 512 + hcol] = hreg[r];
        out[16777216 + 131072 + ((size_t)layer * 64 + bidx) * 512 + hcol] = cnreg[r];
      }
    }

    // ---- end polls: validate iteration t+1's inputs ----
    // wave0 lanes 0-31: cross flag >= t+2; lanes 32-63: self flags >= t+1
    // wave1 lanes 0-31: ring credit
    if (t < 511) {
      if (vm == 0) {
        const unsigned* fp = flags;
        unsigned need = 0;
        if (lane < 32) {
          if (layer > 0) {
            fp = flags + ((layer - 1) * 32 + lane) * 16;
            need = (unsigned)(t + 2);
          }
        } else {
          fp = flags + (layer * 32 + (lane - 32)) * 16;
          need = (unsigned)(t + 1);
        }
        while (true) {
          unsigned v = need ? ld_flag(fp) : 0u;
          if (__ballot(need && v < need) == 0) break;
          __builtin_amdgcn_s_sleep(1);
        }
      } else if (vm == 1) {
        const unsigned* fp = flags;
        unsigned need = 0;
        if (lane < 32 && layer < 3 && (t + 1) >= RING) {
          fp = flags + ((layer + 1) * 32 + lane) * 16;
          need = (unsigned)(t + 2 - RING);
        }
        while (true) {
          unsigned v = need ? ld_flag(fp) : 0u;
          if (__ballot(need && v < need) == 0) break;
          __builtin_amdgcn_s_sleep(1);
        }
      }
      __syncthreads();
      wait_vm0();  // out[] stores + poll loads drained: ladder exact at loop top
    }
  }
}

extern "C" void kernel_launch(void* const* d_in, const int* in_sizes, int n_in,
                              void* d_out, int out_size, void* d_ws, size_t ws_size,
                              hipStream_t stream) {
  const float* x = (const float*)d_in[0];
  const float *W[4], *U[4], *bw[4], *bu[4];
  for (int l = 0; l < 4; ++l) {
    W[l]  = (const float*)d_in[1 + 4 * l];
    U[l]  = (const float*)d_in[2 + 4 * l];
    bw[l] = (const float*)d_in[3 + 4 * l];
    bu[l] = (const float*)d_in[4 + 4 * l];
  }

  char* ws = (char*)d_ws;
  unsigned short* xfrag = (unsigned short*)(ws + 0);        // 16,777,216
  unsigned short* wfr0  = (unsigned short*)(ws + 16777216); //  3,145,728
  unsigned short* wfr1  = (unsigned short*)(ws + 19922944); //  4,194,304
  unsigned short* wfr2  = (unsigned short*)(ws + 24117248); //  4,194,304
  unsigned short* wfr3  = (unsigned short*)(ws + 28311552); //  4,194,304
  float*          biasp = (float*)(ws + 32505856);          //     32,768
  unsigned short* hbuf  = (unsigned short*)(ws + 32538624); //  2,097,152
  unsigned int*   flags = (unsigned int*)(ws + 34635776);   //      8,192
  float* out = (float*)d_out;

  cvt_x_kernel<<<4096, 256, 0, stream>>>(x, xfrag);
  cvt_w_kernel<<<768, 256, 0, stream>>>(W[0], U[0], wfr0, 24, 256);
  cvt_w_kernel<<<1024, 256, 0, stream>>>(W[1], U[1], wfr1, 32, 512);
  cvt_w_kernel<<<1024, 256, 0, stream>>>(W[2], U[2], wfr2, 32, 512);
  cvt_w_kernel<<<1024, 256, 0, stream>>>(W[3], U[3], wfr3, 32, 512);
  bias_kernel<<<8, 256, 0, stream>>>(bw[0], bu[0], biasp + 0 * 2048);
  bias_kernel<<<8, 256, 0, stream>>>(bw[1], bu[1], biasp + 1 * 2048);
  bias_kernel<<<8, 256, 0, stream>>>(bw[2], bu[2], biasp + 2 * 2048);
  bias_kernel<<<8, 256, 0, stream>>>(bw[3], bu[3], biasp + 3 * 2048);
  zero_flags<<<8, 256, 0, stream>>>(flags);

  hipFuncSetAttribute((const void*)lstm_main,
                      hipFuncAttributeMaxDynamicSharedMemorySize, 135168);
  lstm_main<<<dim3(4 * WPL), dim3(NT), 135168, stream>>>(
      xfrag, wfr0, wfr1, wfr2, wfr3, biasp, hbuf, flags, out);
}

// Round 16
// 1898.189 us; speedup vs baseline: 1.4249x; 1.0904x over previous
//
#include <hip/hip_runtime.h>

typedef __attribute__((ext_vector_type(8))) short bf16x8;
typedef __attribute__((ext_vector_type(4))) float f32x4;

// B=64, T=512, D=256, H=512, L=4, 4H=2048
// 32 wgs per layer (16 hcols each), 256 threads (4 waves) per wg. Grid 128.
// All h/flag exchange via LLC (sc0 sc1). Per-step split schedule
// W-GEMM | self-poll | U-GEMM so the self-dependency flag latency hides
// under the W-part matmul. == round-8 kernel (best measured: 1853 us).
#define WPL 32
#define NT 256
#define RING 8

__device__ __forceinline__ unsigned short f2bf(float f) {
  unsigned int u = __float_as_uint(f);
  u += 0x7FFFu + ((u >> 16) & 1u);
  return (unsigned short)(u >> 16);
}
__device__ __forceinline__ float sigmoid_fast(float x) {
  return __builtin_amdgcn_rcpf(1.0f + __builtin_amdgcn_exp2f(-1.4426950408889634f * x));
}
__device__ __forceinline__ float tanh_fast(float x) {
  return 1.0f - 2.0f * __builtin_amdgcn_rcpf(
                           1.0f + __builtin_amdgcn_exp2f(2.885390081777927f * x));
}
__device__ __forceinline__ void wait_vm0() {
  asm volatile("s_waitcnt vmcnt(0)" ::: "memory");
  __builtin_amdgcn_sched_barrier(0);
}
#define WAITVM(N)                                         \
  do {                                                    \
    asm volatile("s_waitcnt vmcnt(" #N ")" ::: "memory"); \
    __builtin_amdgcn_sched_barrier(0);                    \
  } while (0)

// MODE: 0 = plain cached (read-only x), 2 = sc0 sc1 (LLC coherent h)
template <int MODE>
__device__ __forceinline__ void ldA(bf16x8& d, int voff, const unsigned short* base) {
  if constexpr (MODE == 0)
    asm volatile("global_load_dwordx4 %0, %1, %2"
                 : "=v"(d) : "v"(voff), "s"(base));
  else
    asm volatile("global_load_dwordx4 %0, %1, %2 sc0 sc1"
                 : "=v"(d) : "v"(voff), "s"(base));
}
__device__ __forceinline__ unsigned ld_flag(const unsigned* p) {
  unsigned v;
  asm volatile("global_load_dword %0, %1, off sc0 sc1\n\ts_waitcnt vmcnt(0)"
               : "=v"(v) : "v"(p) : "memory");
  return v;
}
__device__ __forceinline__ void st16_coh(void* p, f32x4 v) {
  asm volatile("global_store_dwordx4 %0, %1, off sc0 sc1" :: "v"(p), "v"(v) : "memory");
}
__device__ __forceinline__ void st4_coh(void* p, unsigned v) {
  asm volatile("global_store_dword %0, %1, off sc0 sc1" :: "v"(p), "v"(v) : "memory");
}

// ---------------- prep kernels ----------------

// x [B,T,D] f32 -> xfrag [T][c(8)][bt(4)][lane(64)][e(8)] bf16, lane-linear
__global__ void cvt_x_kernel(const float* __restrict__ x,
                             unsigned short* __restrict__ xf) {
  int tid = blockIdx.x * 256 + threadIdx.x;  // 1,048,576
  int t     = tid >> 11;
  int inner = tid & 2047;
  int lane  = inner & 63;
  int bt    = (inner >> 6) & 3;
  int c     = inner >> 8;
  int b = bt * 16 + (lane & 15);
  int d = c * 32 + (lane >> 4) * 8;
  const float* s = x + ((size_t)b * 512 + t) * 256 + d;
  f32x4 v0 = *(const f32x4*)s;
  f32x4 v1 = *(const f32x4*)(s + 4);
  bf16x8 o;
  o[0] = (short)f2bf(v0[0]); o[1] = (short)f2bf(v0[1]);
  o[2] = (short)f2bf(v0[2]); o[3] = (short)f2bf(v0[3]);
  o[4] = (short)f2bf(v1[0]); o[5] = (short)f2bf(v1[1]);
  o[6] = (short)f2bf(v1[2]); o[7] = (short)f2bf(v1[3]);
  *(bf16x8*)(xf + (size_t)t * 16384 + (size_t)inner * 8) = o;
}

// W/U f32 -> wfrag [w(32)][g(4)][c(C2)][lane(64)][e(8)] bf16
__global__ void cvt_w_kernel(const float* __restrict__ W,
                             const float* __restrict__ U,
                             unsigned short* __restrict__ dst,
                             int C2, int split) {
  int tid = blockIdx.x * 256 + threadIdx.x;
  int lane = tid & 63;
  int c    = (tid >> 6) % C2;
  int rest = tid / (64 * C2);
  int g = rest & 3;
  int w = rest >> 2;
  int row = g * 512 + w * 16 + (lane & 15);
  int k   = c * 32 + (lane >> 4) * 8;
  const float* s = (k < split) ? (W + (size_t)row * split + k)
                               : (U + (size_t)row * 512 + (k - split));
  f32x4 v0 = *(const f32x4*)s;
  f32x4 v1 = *(const f32x4*)(s + 4);
  bf16x8 o;
  o[0] = (short)f2bf(v0[0]); o[1] = (short)f2bf(v0[1]);
  o[2] = (short)f2bf(v0[2]); o[3] = (short)f2bf(v0[3]);
  o[4] = (short)f2bf(v1[0]); o[5] = (short)f2bf(v1[1]);
  o[6] = (short)f2bf(v1[2]); o[7] = (short)f2bf(v1[3]);
  *(bf16x8*)(dst + (size_t)tid * 8) = o;
}

__global__ void bias_kernel(const float* __restrict__ bw,
                            const float* __restrict__ bu,
                            float* __restrict__ dst) {
  int i = blockIdx.x * 256 + threadIdx.x;  // 2048
  dst[i] = bw[i] + bu[i];
}

__global__ void zero_flags(unsigned int* __restrict__ p) {
  int i = blockIdx.x * 256 + threadIdx.x;  // 2048
  p[i] = 0u;
}

// ---------------- pipelined partial GEMM (NC k-chunks from one base) ----------------
// A from global frag layout; B from LDS frag layout (bg pre-offset by caller).
// 3-phase-deep A pipeline with counted vmcnt. Requires vmcnt==0 at entry;
// leaves vmcnt==0 at exit.
template <int NC, int MODE>
__device__ __forceinline__ void gemm_part(const unsigned short* __restrict__ a,
                                          const char* bg0, const char* bg1,
                                          const char* bg2, const char* bg3,
                                          int voffA, f32x4 acc[4]) {
  constexpr int NP = NC / 4;
  bf16x8 av[3][4];
  bf16x8 bb[2][4][4];
  const char* bgp[4] = {bg0, bg1, bg2, bg3};

  auto issueA_phase = [&](int q) {
#pragma unroll
    for (int i = 0; i < 4; ++i)
      ldA<MODE>(av[q % 3][i], voffA + (4 * q + i) * 4096, a);
  };
  auto loadB_phase = [&](int q) {
#pragma unroll
    for (int i = 0; i < 4; ++i)
#pragma unroll
      for (int g = 0; g < 4; ++g)
        bb[q & 1][i][g] = *(const bf16x8*)(bgp[g] + (4 * q + i) * 1024);
  };

#pragma unroll
  for (int q = 0; q < 3; ++q)
    if (q < NP) issueA_phase(q);
  loadB_phase(0);

#pragma unroll
  for (int ph = 0; ph < NP; ++ph) {
    if (ph + 1 < NP) loadB_phase(ph + 1);
    if (ph < NP - 2) {
      WAITVM(8);
    } else if (ph == NP - 2) {
      WAITVM(4);
    } else {
      WAITVM(0);
    }
#pragma unroll
    for (int i = 0; i < 4; ++i)
#pragma unroll
      for (int g = 0; g < 4; ++g)
        acc[g] = __builtin_amdgcn_mfma_f32_16x16x32_bf16(av[ph % 3][i],
                                                         bb[ph & 1][i][g],
                                                         acc[g], 0, 0, 0);
    if (ph + 3 < NP) issueA_phase(ph + 3);
  }
}

// ---------------- main persistent kernel ----------------
// grid 128: layer = bid>>5, w = bid&31 (hcols w*16..+16).
// 4 waves: wave vm owns m-tile rows vm*16..+16, full K.
__global__ void __launch_bounds__(NT, 1)
lstm_main(const unsigned short* __restrict__ xfrag,
          const unsigned short* __restrict__ wf0,
          const unsigned short* __restrict__ wf1,
          const unsigned short* __restrict__ wf2,
          const unsigned short* __restrict__ wf3,
          const float* __restrict__ bias,
          unsigned short* __restrict__ hbuf,
          unsigned int* __restrict__ flags,
          float* __restrict__ out) {
  extern __shared__ char smem[];

  const int bid   = blockIdx.x;
  const int layer = bid >> 5;
  const int w     = bid & 31;
  const int tid   = threadIdx.x;
  const int lane  = tid & 63;
  const int vm    = tid >> 6;
  const int l15   = lane & 15;
  const int lhi   = lane >> 4;
  const int hcol  = w * 16 + l15;
  const int C2r   = (layer == 0) ? 24 : 32;
  const int C1w   = (layer == 0) ? 8 : 16;   // W-part chunks
  const int HOFF  = 4 * C2r * 64 * 16;       // LDS h-transpose buffer offset

  const unsigned short* wfl =
      (layer == 0) ? wf0 : (layer == 1) ? wf1 : (layer == 2) ? wf2 : wf3;
  const unsigned short* wsl = wfl + (size_t)w * (4 * C2r * 64 * 8);

  // stage weights into LDS (frag-linear; one-time)
  for (int i = tid; i < 4 * C2r * 64; i += NT)
    *(f32x4*)(smem + (size_t)i * 16) = *(const f32x4*)(wsl + (size_t)i * 8);
  __syncthreads();

  const char* bgW[4];
  const char* bgU[4];
#pragma unroll
  for (int g = 0; g < 4; ++g) {
    bgW[g] = smem + ((size_t)g * C2r * 64 + lane) * 16;
    bgU[g] = bgW[g] + (size_t)C1w * 1024;
  }

  float bv[4];
#pragma unroll
  for (int g = 0; g < 4; ++g) bv[g] = bias[layer * 2048 + g * 512 + hcol];

  float creg[4];
#pragma unroll
  for (int r = 0; r < 4; ++r) creg[r] = 0.f;

  const int voffA = lane * 16 + vm * 1024;
  const int base_w = (w >> 1) * 2048 + (w & 1) * 256;  // shorts

  const unsigned short* hprev =
      (layer == 0) ? nullptr : (hbuf + (size_t)(layer - 1) * RING * 32768);
  const unsigned short* hself = hbuf + (size_t)layer * RING * 32768;

  // h publish store thread mapping (tid < 128)
  const int sb_bt = tid >> 5;
  const int sb_q  = (tid >> 4) & 1;
  const int sb_bl = tid & 15;
  const int slot_off = base_w + sb_bt * 512 + sb_q * 128 + sb_bl * 8;

  for (int t = 0; t < 512; ++t) {
    // ---- barrier A: cross-dep (wave0) + ring credit (wave1) ----
    if (vm == 0) {
      const unsigned* fp = flags;
      unsigned need = 0;
      if (lane < 32 && layer > 0) {
        fp = flags + ((layer - 1) * 32 + lane) * 16;
        need = (unsigned)(t + 1);
      }
      while (true) {
        unsigned v = need ? ld_flag(fp) : 0u;
        if (__ballot(need && v < need) == 0) break;
        __builtin_amdgcn_s_sleep(1);
      }
    } else if (vm == 1) {
      const unsigned* fp = flags;
      unsigned need = 0;
      if (lane < 32 && layer < 3 && t >= RING) {
        fp = flags + ((layer + 1) * 32 + lane) * 16;
        need = (unsigned)(t - RING + 1);
      }
      while (true) {
        unsigned v = need ? ld_flag(fp) : 0u;
        if (__ballot(need && v < need) == 0) break;
        __builtin_amdgcn_s_sleep(1);
      }
    }
    __syncthreads();
    wait_vm0();  // drain stray (out[]) stores so counted vmcnt is exact

    f32x4 acc[4];
    const f32x4 z4 = {0.f, 0.f, 0.f, 0.f};
#pragma unroll
    for (int g = 0; g < 4; ++g) acc[g] = z4;

    // ---- W-part GEMM (cross/x input only) ----
    if (layer == 0)
      gemm_part<8, 0>(xfrag + (size_t)t * 16384,
                      bgW[0], bgW[1], bgW[2], bgW[3], voffA, acc);
    else
      gemm_part<16, 2>(hprev + (size_t)(t & (RING - 1)) * 32768,
                       bgW[0], bgW[1], bgW[2], bgW[3], voffA, acc);

    // ---- barrier B: self-dep poll (hidden under W-part above) ----
    if (t > 0) {
      if (vm == 0) {
        const unsigned* fp = flags;
        unsigned need = 0;
        if (lane < 32) {
          fp = flags + (layer * 32 + lane) * 16;
          need = (unsigned)t;
        }
        while (true) {
          unsigned v = need ? ld_flag(fp) : 0u;
          if (__ballot(need && v < need) == 0) break;
          __builtin_amdgcn_s_sleep(1);
        }
      }
      __syncthreads();

      // ---- U-part GEMM (self h(t-1)) ----
      gemm_part<16, 2>(hself + (size_t)((t - 1) & (RING - 1)) * 32768,
                       bgU[0], bgU[1], bgU[2], bgU[3], voffA, acc);
    }

    // ---- gates + state; h -> LDS transpose ----
    float hreg[4], cnreg[4];
#pragma unroll
    for (int r = 0; r < 4; ++r) {
      float fg = sigmoid_fast(acc[0][r] + bv[0]);
      float ig = sigmoid_fast(acc[1][r] + bv[1]);
      float og = sigmoid_fast(acc[2][r] + bv[2]);
      float gg = tanh_fast(acc[3][r] + bv[3]);
      float cn = fg * creg[r] + ig * gg;
      creg[r] = cn;
      cnreg[r] = cn;
      float h = og * tanh_fast(cn);
      hreg[r] = h;
      *(unsigned short*)(smem + HOFF + (vm * 16 + lhi * 4 + r) * 32 + l15 * 2) =
          f2bf(h);
    }
    __syncthreads();

    // ---- coalesced coherent h publish (threads 0..127) ----
    if (tid < 128) {
      f32x4 hv = *(const f32x4*)(smem + HOFF + (sb_bt * 16 + sb_bl) * 32 + sb_q * 16);
      unsigned short* dst = hbuf +
          ((size_t)layer * RING + (t & (RING - 1))) * 32768 + slot_off;
      st16_coh(dst, hv);
      wait_vm0();
    }
    __syncthreads();
    if (tid == 0)
      st4_coh(flags + (layer * 32 + w) * 16, (unsigned)(t + 1));

    // ---- output stores (off the critical chain) ----
    if (layer == 3) {
#pragma unroll
      for (int r = 0; r < 4; ++r) {
        int bidx = vm * 16 + lhi * 4 + r;
        out[(size_t)bidx * 262144 + (size_t)t * 512 + hcol] = hreg[r];
      }
    }
    if (t == 511) {
#pragma unroll
      for (int r = 0; r < 4; ++r) {
        int bidx = vm * 16 + lhi * 4 + r;
        out[16777216 + ((size_t)layer * 64 + bidx) * 512 + hcol] = hreg[r];
        out[16777216 + 131072 + ((size_t)layer * 64 + bidx) * 512 + hcol] = cnreg[r];
      }
    }
  }
}

extern "C" void kernel_launch(void* const* d_in, const int* in_sizes, int n_in,
                              void* d_out, int out_size, void* d_ws, size_t ws_size,
                              hipStream_t stream) {
  const float* x = (const float*)d_in[0];
  const float *W[4], *U[4], *bw[4], *bu[4];
  for (int l = 0; l < 4; ++l) {
    W[l]  = (const float*)d_in[1 + 4 * l];
    U[l]  = (const float*)d_in[2 + 4 * l];
    bw[l] = (const float*)d_in[3 + 4 * l];
    bu[l] = (const float*)d_in[4 + 4 * l];
  }

  char* ws = (char*)d_ws;
  unsigned short* xfrag = (unsigned short*)(ws + 0);        // 16,777,216
  unsigned short* wfr0  = (unsigned short*)(ws + 16777216); //  3,145,728
  unsigned short* wfr1  = (unsigned short*)(ws + 19922944); //  4,194,304
  unsigned short* wfr2  = (unsigned short*)(ws + 24117248); //  4,194,304
  unsigned short* wfr3  = (unsigned short*)(ws + 28311552); //  4,194,304
  float*          biasp = (float*)(ws + 32505856);          //     32,768
  unsigned short* hbuf  = (unsigned short*)(ws + 32538624); //  2,097,152
  unsigned int*   flags = (unsigned int*)(ws + 34635776);   //      8,192
  float* out = (float*)d_out;

  cvt_x_kernel<<<4096, 256, 0, stream>>>(x, xfrag);
  cvt_w_kernel<<<768, 256, 0, stream>>>(W[0], U[0], wfr0, 24, 256);
  cvt_w_kernel<<<1024, 256, 0, stream>>>(W[1], U[1], wfr1, 32, 512);
  cvt_w_kernel<<<1024, 256, 0, stream>>>(W[2], U[2], wfr2, 32, 512);
  cvt_w_kernel<<<1024, 256, 0, stream>>>(W[3], U[3], wfr3, 32, 512);
  bias_kernel<<<8, 256, 0, stream>>>(bw[0], bu[0], biasp + 0 * 2048);
  bias_kernel<<<8, 256, 0, stream>>>(bw[1], bu[1], biasp + 1 * 2048);
  bias_kernel<<<8, 256, 0, stream>>>(bw[2], bu[2], biasp + 2 * 2048);
  bias_kernel<<<8, 256, 0, stream>>>(bw[3], bu[3], biasp + 3 * 2048);
  zero_flags<<<8, 256, 0, stream>>>(flags);

  hipFuncSetAttribute((const void*)lstm_main,
                      hipFuncAttributeMaxDynamicSharedMemorySize, 135168);
  lstm_main<<<dim3(4 * WPL), dim3(NT), 135168, stream>>>(
      xfrag, wfr0, wfr1, wfr2, wfr3, biasp, hbuf, flags, out);
}